// Round 6
// baseline (1485.425 us; speedup 1.0000x reference)
//
#include <hip/hip_runtime.h>
#include <hip/hip_bf16.h>

typedef __hip_bfloat16 bf16;
typedef __attribute__((ext_vector_type(8))) short short8;
typedef __attribute__((ext_vector_type(4))) float f32x4;

#define NN 50000
#define RR 6
#define EE 32768
#define HH 256
#define FF 16
#define NHEAD 8
#define KVP 320   // 272 padded to multiple of 64

struct __align__(8) bf16x4 { bf16 v[4]; };

__device__ __forceinline__ float b2f(bf16 v) { return __bfloat162float(v); }
__device__ __forceinline__ bf16 f2b(float v) { return __float2bfloat16(v); }
__device__ __forceinline__ short f2s(float f) { bf16 b = f2b(f); return __builtin_bit_cast(short, b); }
__device__ __forceinline__ float s2f(short s) { return b2f(__builtin_bit_cast(bf16, s)); }
__device__ __forceinline__ float gelu_f(float x) { return 0.5f * x * (1.0f + erff(x * 0.7071067811865476f)); }

// async global->LDS, 16B per lane (dest = wave-uniform base + lane*16;
// the GLOBAL address may be fully per-lane -> gather-capable)
__device__ __forceinline__ void gl2lds16(const void* g, void* l) {
  __builtin_amdgcn_global_load_lds(
      (const __attribute__((address_space(1))) unsigned int*)g,
      (__attribute__((address_space(3))) unsigned int*)l, 16, 0, 0);
}

// grid-stride zero fill (16B granules)
__global__ void zero_k(uint4* __restrict__ p, int n16)
{
  const uint4 z = make_uint4(0u, 0u, 0u, 0u);
  for (int i = blockIdx.x * blockDim.x + threadIdx.x; i < n16; i += gridDim.x * blockDim.x)
    p[i] = z;
}

// fp32 -> bf16 elementwise (4 per thread)
__global__ void cvt_k(const float* __restrict__ in, bf16* __restrict__ out, int n4)
{
  const int i = blockIdx.x * 256 + threadIdx.x;
  if (i >= n4) return;
  const float4 f = ((const float4*)in)[i];
  bf16x4 o; o.v[0] = f2b(f.x); o.v[1] = f2b(f.y); o.v[2] = f2b(f.z); o.v[3] = f2b(f.w);
  ((bf16x4*)out)[i] = o;
}

// transpose-convert: in fp32 [K][NC] -> out bf16 [NC][Kp], zero-pad K..Kp.
__global__ void tconv_k(const float* __restrict__ in, bf16* __restrict__ out,
                        int K, int NC, int Kp, long izs, long ozs)
{
  __shared__ float t[32][33];
  in  += (size_t)blockIdx.z * izs;
  out += (size_t)blockIdx.z * ozs;
  const int kb = blockIdx.x * 32, nb = blockIdx.y * 32;
  const int tx = threadIdx.x & 31, ty = threadIdx.x >> 5;  // ty 0..7
  for (int i = ty; i < 32; i += 8) {
    const int k = kb + i, n = nb + tx;
    t[i][tx] = (k < K && n < NC) ? in[(size_t)k * NC + n] : 0.f;
  }
  __syncthreads();
  for (int i = ty; i < 32; i += 8) {
    const int n = nb + i, k = kb + tx;
    if (n < NC && k < Kp) out[(size_t)n * Kp + k] = f2b(t[tx][i]);
  }
}

// build concatenated kv bias: bkv[r][0..255]=bk[r], bkv[r][256..511]=bv[r]
__global__ void bkv_k(const float* __restrict__ bk, const float* __restrict__ bv,
                      float* __restrict__ bkv)
{
  const int i = blockIdx.x * 256 + threadIdx.x;
  if (i >= RR * 512) return;
  const int r = i >> 9, c = i & 511;
  bkv[i] = (c < 256) ? bk[r * 256 + c] : bv[r * 256 + (c - 256)];
}

// copy tmp [N][256] bf16 -> rel_cat slot (ld 1536)
__global__ void copyslot_k(const bf16* __restrict__ tmp, bf16* __restrict__ slot)
{
  const int i = blockIdx.x * 256 + threadIdx.x;  // 8-elem chunk id
  if (i >= NN * 32) return;
  const int n = i >> 5, c = (i & 31) * 8;
  *(short8*)(slot + (size_t)n * 1536 + c) = *(const short8*)(tmp + (size_t)n * 256 + c);
}

// ---------------------------------------------------------------------------
// MFMA GEMM with COUNTED-VMCNT double-buffered pipeline (T4, m218):
// C[M,NC] = act(A[M,K] @ Bt^T + bias), Bt = [NC][K] bf16 k-contig.
// 128x128 tile, BK=64, 4 waves, wave = 64x64 (4x4 of 16x16x32 MFMA).
// Per K-step t: issue stage(t+1) -> s_waitcnt vmcnt(N) [N = this iter's
// issues; drains EXACTLY tile t's loads since all of this iter's are newer]
// -> raw s_barrier -> compute(t) -> [write-late reg-staged A] -> lgkmcnt(0)
// + raw barrier. Prefetched loads stay in flight ACROSS barriers (the
// __syncthreads vmcnt(0) drain was the 1-phase stall). 64KB LDS -> 2
// blocks/CU (traded TLP for pipeline depth).
// LDS chunk (row, cg) holds global chunk cg ^ (row&7) (bank swizzle).
// ASRC: 0=A bf16 gl2lds; 2=PAIR bf16 sum (reg-staged, write-late);
//       3=KV gather PURE gl2lds (per-lane addr: xb[src]|eab|zpad via dnm);
//       4=A fp32 * 1/(dnm[row,head]+1e-16) (reg-staged, write-late).
// ZMODE: 0=plain; 1=logits (A = rel_cat+slot3[z]*256, tanh-dot epilogue);
//        3=metapath batch (z picks pair slots + B/bias, C += z*M*256).
// ---------------------------------------------------------------------------
template<int ASRC, int ACT, int ZMODE, typename TO>
__global__ __launch_bounds__(256) void mm_k(
    const void* __restrict__ Av, const bf16* __restrict__ A2, int lda,
    const int* __restrict__ src, const bf16* __restrict__ eab,
    const float* __restrict__ dnm,
    const bf16* __restrict__ Bt, const float* __restrict__ bias,
    const float* __restrict__ wa2, TO* __restrict__ C, int ldc,
    float* __restrict__ logits, int M, int K, int z0)
{
  __shared__ short lA[2][128 * 64];
  __shared__ short lB[2][128 * 64];
  const int tid = threadIdx.x;
  const int w = tid >> 6, l = tid & 63;
  const int col0 = blockIdx.x << 7;
  const int row0 = blockIdx.y << 7;
  const bf16* Ab = (const bf16*)Av;
  const bf16* A2b = A2;
  const bf16* Btz = Bt;
  const float* biasz = bias;
  TO* Cz = C;
  float* lg = logits;
  if constexpr (ZMODE == 1) {
    const int slots3[3] = {2, 4, 1};
    Ab = (const bf16*)Av + slots3[blockIdx.z] * 256;
    lg = logits + (size_t)blockIdx.z * M;
  } else if constexpr (ZMODE == 3) {
    const int r1s[3] = {2, 4, 1}, r2s[3] = {3, 0, 5};
    const int z = blockIdx.z + z0;
    Ab  = (const bf16*)Av + (size_t)r1s[z] * 256;
    A2b = A2 + (size_t)r2s[z] * 256;
    Btz = Bt + (size_t)z * 256 * K;
    biasz = bias + z * 256;
    Cz = C + (size_t)blockIdx.z * (size_t)M * 256;
  }
  const int wm = (w >> 1) << 6, wn = (w & 1) << 6;
  const int lane15 = l & 15, kq = l >> 4;

  // loop-invariant staging geometry (idx = 16B chunk id 0..1023)
  int idx8[4], rowic[4], scg8[4], ri[4], si[4];
#pragma unroll
  for (int i = 0; i < 4; ++i) {
    const int idx = (w * 4 + i) * 64 + l;
    rowic[i] = idx >> 3;
    scg8[i]  = ((idx & 7) ^ (rowic[i] & 7)) * 8;   // swizzled k-offset (elems)
    idx8[i]  = idx * 8;
    ri[i]    = min(row0 + rowic[i], M - 1);
    if constexpr (ASRC == 3) si[i] = src[ri[i]];
  }

  short8 ps[4], ps2[4]; float4 pf[8];

  auto stageB = [&](int t, int b) {
#pragma unroll
    for (int i = 0; i < 4; ++i)
      gl2lds16(Btz + (size_t)(col0 + rowic[i]) * K + (t << 6) + scg8[i], &lB[b][idx8[i]]);
  };
  auto stageA = [&](int t, int b) {
    const int k0 = t << 6;
#pragma unroll
    for (int i = 0; i < 4; ++i) {
      const int kc = k0 + scg8[i];
      if constexpr (ASRC == 0) {
        gl2lds16(Ab + (size_t)ri[i] * lda + kc, &lA[b][idx8[i]]);
      } else if constexpr (ASRC == 3) {
        const bf16* p = (kc < HH) ? (const bf16*)Av + (size_t)si[i] * HH + kc
                      : (kc < HH + FF) ? eab + (size_t)ri[i] * FF + (kc - HH)
                      : (const bf16*)dnm;   // dnm doubles as 16B zeroed zpad
        gl2lds16(p, &lA[b][idx8[i]]);
      } else if constexpr (ASRC == 2) {
        ps[i]  = *(const short8*)(Ab  + (size_t)ri[i] * lda + kc);
        ps2[i] = *(const short8*)(A2b + (size_t)ri[i] * lda + kc);
      } else {  // ASRC == 4
        const float* p = (const float*)Av + (size_t)ri[i] * lda + kc;
        pf[2 * i] = *(const float4*)p; pf[2 * i + 1] = *(const float4*)(p + 4);
      }
    }
  };
  auto writeA = [&](int t, int b) {   // reg-staged write-late (ASRC 2/4)
    const int k0 = t << 6;
    if constexpr (ASRC == 2) {
#pragma unroll
      for (int i = 0; i < 4; ++i) {
        short8 s;
#pragma unroll
        for (int j = 0; j < 8; ++j) s[j] = f2s(s2f(ps[i][j]) + s2f(ps2[i][j]));
        *(short8*)&lA[b][idx8[i]] = s;
      }
    } else if constexpr (ASRC == 4) {
#pragma unroll
      for (int i = 0; i < 4; ++i) {
        const int kc = k0 + scg8[i];
        const float iv = 1.0f / (dnm[ri[i] * NHEAD + (kc >> 5)] + 1e-16f);
        short8 s;
        s[0] = f2s(pf[2*i].x * iv); s[1] = f2s(pf[2*i].y * iv);
        s[2] = f2s(pf[2*i].z * iv); s[3] = f2s(pf[2*i].w * iv);
        s[4] = f2s(pf[2*i+1].x * iv); s[5] = f2s(pf[2*i+1].y * iv);
        s[6] = f2s(pf[2*i+1].z * iv); s[7] = f2s(pf[2*i+1].w * iv);
        *(short8*)&lA[b][idx8[i]] = s;
      }
    }
  };

  f32x4 acc[4][4] = {};
  const int NT = K >> 6;

  // ---- prologue: stage tile 0 into buf 0 ----
  stageA(0, 0);
  stageB(0, 0);
  if constexpr (ASRC == 2 || ASRC == 4) writeA(0, 0);  // compiler waits on deps

  int cur = 0;
  for (int t = 0; t < NT; ++t) {
    const int nb = cur ^ 1;
    if (t + 1 < NT) {
      stageA(t + 1, nb);
      stageB(t + 1, nb);
      // drain exactly tile t's loads; tile t+1's stay in flight across barrier
      if constexpr (ASRC == 0 || ASRC == 3)
        asm volatile("s_waitcnt vmcnt(8) lgkmcnt(0)" ::: "memory");
      else
        asm volatile("s_waitcnt vmcnt(12) lgkmcnt(0)" ::: "memory");
    } else {
      asm volatile("s_waitcnt vmcnt(0) lgkmcnt(0)" ::: "memory");
    }
    __builtin_amdgcn_s_barrier();
    __builtin_amdgcn_sched_barrier(0);
    // ---- compute on buf cur ----
#pragma unroll
    for (int kk = 0; kk < 64; kk += 32) {
      short8 af[4], bfr[4];
#pragma unroll
      for (int tt = 0; tt < 4; ++tt) {
        const int ra = wm + tt * 16 + lane15;
        const int ca = ((kk >> 3) + kq) ^ (ra & 7);
        af[tt] = *(const short8*)&lA[cur][ra * 64 + ca * 8];
        const int rb = wn + tt * 16 + lane15;
        const int cb = ((kk >> 3) + kq) ^ (rb & 7);
        bfr[tt] = *(const short8*)&lB[cur][rb * 64 + cb * 8];
      }
#pragma unroll
      for (int ti = 0; ti < 4; ++ti)
#pragma unroll
        for (int tj = 0; tj < 4; ++tj)
          acc[ti][tj] = __builtin_amdgcn_mfma_f32_16x16x32_bf16(af[ti], bfr[tj], acc[ti][tj], 0, 0, 0);
    }
    if (t + 1 < NT) {
      if constexpr (ASRC == 2 || ASRC == 4) writeA(t + 1, nb);
      // reads of cur done + reg-staged writes visible before overwrite/use
      asm volatile("s_waitcnt lgkmcnt(0)" ::: "memory");
      __builtin_amdgcn_s_barrier();
      __builtin_amdgcn_sched_barrier(0);
    }
    cur = nb;
  }

  if constexpr (ZMODE != 1) {
    // C layout: col = lane&15, row = (lane>>4)*4 + reg  [m89-verified]
#pragma unroll
    for (int ti = 0; ti < 4; ++ti) {
#pragma unroll
      for (int reg = 0; reg < 4; ++reg) {
        const int row = row0 + wm + ti * 16 + kq * 4 + reg;
        if (row >= M) continue;
#pragma unroll
        for (int tj = 0; tj < 4; ++tj) {
          const int col = col0 + wn + tj * 16 + lane15;
          float v = acc[ti][tj][reg] + biasz[col];
          if constexpr (ACT == 1) v = gelu_f(v);
          if constexpr (sizeof(TO) == 2) Cz[(size_t)row * ldc + col] = (TO)f2b(v);
          else                           Cz[(size_t)row * ldc + col] = (TO)v;
        }
      }
    }
  } else {
#pragma unroll
    for (int ti = 0; ti < 4; ++ti) {
#pragma unroll
      for (int reg = 0; reg < 4; ++reg) {
        float part = 0.f;
#pragma unroll
        for (int tj = 0; tj < 4; ++tj) {
          const int col = col0 + wn + tj * 16 + lane15;
          part += tanhf(acc[ti][tj][reg] + biasz[col]) * wa2[col];
        }
#pragma unroll
        for (int off = 8; off > 0; off >>= 1) part += __shfl_xor(part, off, 64);
        const int row = row0 + wm + ti * 16 + kq * 4 + reg;
        if (lane15 == 0 && row < M) atomicAdd(&lg[row], part);
      }
    }
  }
}

// ---------------------------------------------------------------------------
// Fused edge pass (round-5 proven): per edge e (one 256-thread block):
//   s_h = (sum q[dst]*k[e]) * scale * prior[h]; ex = exp(s) (no max: softmax
//   shift-invariant, scores O(1)); denom[dst,h] += ex; agg[dst,:] += ex*v[e].
// ---------------------------------------------------------------------------
__global__ void edge_k(const bf16* __restrict__ q, const bf16* __restrict__ kv,
                       const int* __restrict__ dst_idx, const float* __restrict__ prior_r,
                       float* __restrict__ denom, float* __restrict__ agg)
{
  const int e = blockIdx.x, t = threadIdx.x;
  const int dst = dst_idx[e];
  const int h = t >> 5;
  float p = b2f(q[(size_t)dst * 1536 + t]) * b2f(kv[(size_t)e * 512 + t]);
#pragma unroll
  for (int off = 16; off > 0; off >>= 1) p += __shfl_down(p, off, 32);
  const float s = __shfl(p, 0, 32);   // broadcast head sum within 32-group
  const float ex = expf(s * 0.1767766952966369f * prior_r[h]);
  if ((t & 31) == 0) atomicAdd(&denom[dst * NHEAD + h], ex);
  atomicAdd(&agg[(size_t)dst * HH + t], ex * b2f(kv[(size_t)e * 512 + 256 + t]));
}

// ---------------------------------------------------------------------------
// inter-relation softmax weights; one wave per node
// ---------------------------------------------------------------------------
__global__ void interw_k(const bf16* __restrict__ h, const float* __restrict__ W2,
                         const float* __restrict__ b2, float* __restrict__ interw)
{
  const int wv = threadIdx.x >> 6, ln = threadIdx.x & 63;
  const int n = blockIdx.x * 4 + wv;
  if (n >= NN) return;
  float a[6] = {0.f, 0.f, 0.f, 0.f, 0.f, 0.f};
#pragma unroll
  for (int kq = 0; kq < 4; ++kq) {
    const int k = ln + (kq << 6);
    const float hv = b2f(h[(size_t)n * HH + k]);
#pragma unroll
    for (int j = 0; j < 6; ++j) a[j] += hv * W2[k * 6 + j];
  }
#pragma unroll
  for (int j = 0; j < 6; ++j) {
#pragma unroll
    for (int off = 32; off > 0; off >>= 1) a[j] += __shfl_down(a[j], off, 64);
  }
  if (ln == 0) {
    float lg[6], e[6], mx = -1e30f, s = 0.f;
#pragma unroll
    for (int j = 0; j < 6; ++j) { lg[j] = a[j] + b2[j]; mx = fmaxf(mx, lg[j]); }
#pragma unroll
    for (int j = 0; j < 6; ++j) { e[j] = expf(lg[j] - mx); s += e[j]; }
    const float inv = 1.0f / s;
#pragma unroll
    for (int j = 0; j < 6; ++j) interw[(size_t)n * 6 + j] = e[j] * inv;
  }
}

// rel_cat layout: [N][R*256]
__global__ void interagg_k(const float* __restrict__ interw, const bf16* __restrict__ rel_cat,
                           bf16* __restrict__ comb)
{
  const int n = blockIdx.x, t = threadIdx.x;
  float acc = 0.f;
#pragma unroll
  for (int r = 0; r < 6; ++r)
    acc += interw[(size_t)n * 6 + r] * b2f(rel_cat[(size_t)n * 1536 + r * 256 + t]);
  comb[(size_t)n * 512 + t] = f2b(acc);
}

// ---------------------------------------------------------------------------
// meta final: softmax(logits[3]) -> weighted sum of stacked -> LN -> comb[:,256:]
// ---------------------------------------------------------------------------
__global__ void metafinal_k(const float* __restrict__ logits, const bf16* __restrict__ rel_cat,
                            const float* __restrict__ gmeta, const float* __restrict__ bmeta,
                            bf16* __restrict__ comb)
{
  const int wv = threadIdx.x >> 6, ln = threadIdx.x & 63;
  const int n = blockIdx.x * 4 + wv;
  if (n >= NN) return;
  const float l0 = logits[n], l1 = logits[NN + n], l2 = logits[2 * NN + n];
  const float mx = fmaxf(l0, fmaxf(l1, l2));
  const float e0 = expf(l0 - mx), e1 = expf(l1 - mx), e2 = expf(l2 - mx);
  const float inv = 1.0f / (e0 + e1 + e2);
  const float a0 = e0 * inv, a1 = e1 * inv, a2 = e2 * inv;
  const size_t base = (size_t)n * 1536;
  float pre[4], s = 0.f, s2 = 0.f;
#pragma unroll
  for (int q4 = 0; q4 < 4; ++q4) {
    const int j = ln + (q4 << 6);
    const float v = a0 * b2f(rel_cat[base + 2 * 256 + j])
                  + a1 * b2f(rel_cat[base + 4 * 256 + j])
                  + a2 * b2f(rel_cat[base + 1 * 256 + j]);
    pre[q4] = v; s += v; s2 += v * v;
  }
#pragma unroll
  for (int off = 32; off > 0; off >>= 1) { s += __shfl_down(s, off, 64); s2 += __shfl_down(s2, off, 64); }
  s = __shfl(s, 0, 64); s2 = __shfl(s2, 0, 64);
  const float mu = s * (1.0f / 256.0f);
  const float var = s2 * (1.0f / 256.0f) - mu * mu;
  const float rs = rsqrtf(var + 1e-5f);
#pragma unroll
  for (int q4 = 0; q4 < 4; ++q4) {
    const int j = ln + (q4 << 6);
    comb[(size_t)n * 512 + 256 + j] = f2b((pre[q4] - mu) * rs * gmeta[j] + bmeta[j]);
  }
}

// final: out = LN(x + combined)
__global__ void final_k(const float* __restrict__ x, const float* __restrict__ combined,
                        const float* __restrict__ g, const float* __restrict__ b,
                        float* __restrict__ out)
{
  __shared__ float sred[8];
  const int n = blockIdx.x, t = threadIdx.x;
  const float v = x[(size_t)n * HH + t] + combined[(size_t)n * HH + t];
  float s = v, s2 = v * v;
#pragma unroll
  for (int off = 32; off > 0; off >>= 1) { s += __shfl_down(s, off, 64); s2 += __shfl_down(s2, off, 64); }
  const int wv = t >> 6;
  if ((t & 63) == 0) { sred[wv] = s; sred[4 + wv] = s2; }
  __syncthreads();
  const float st = sred[0] + sred[1] + sred[2] + sred[3];
  const float st2 = sred[4] + sred[5] + sred[6] + sred[7];
  const float mu = st * (1.0f / 256.0f);
  const float var = st2 * (1.0f / 256.0f) - mu * mu;
  const float rs = rsqrtf(var + 1e-5f);
  out[(size_t)n * HH + t] = (v - mu) * rs * g[t] + b[t];
}

// ---------------------------------------------------------------------------
extern "C" void kernel_launch(void* const* d_in, const int* in_sizes, int n_in,
                              void* d_out, int out_size, void* d_ws, size_t ws_size,
                              hipStream_t stream)
{
  const float* x      = (const float*)d_in[0];
  const int*   eidx   = (const int*)d_in[1];
  const float* eattr  = (const float*)d_in[2];
  const float* Wq     = (const float*)d_in[3];
  const float* bq     = (const float*)d_in[4];
  const float* Wk     = (const float*)d_in[5];
  const float* bk     = (const float*)d_in[6];
  const float* Wv     = (const float*)d_in[7];
  const float* bv     = (const float*)d_in[8];
  const float* prior  = (const float*)d_in[9];
  const float* Wm     = (const float*)d_in[10];
  const float* bm     = (const float*)d_in[11];
  const float* W_ir1  = (const float*)d_in[12];
  const float* b_ir1  = (const float*)d_in[13];
  const float* W_ir2  = (const float*)d_in[14];
  const float* b_ir2  = (const float*)d_in[15];
  const float* Wmp    = (const float*)d_in[16];
  const float* bmp    = (const float*)d_in[17];
  const float* Wa1    = (const float*)d_in[18];
  const float* ba1    = (const float*)d_in[19];
  const float* Wa2    = (const float*)d_in[20];
  const float* g_meta = (const float*)d_in[21];
  const float* b_meta = (const float*)d_in[22];
  const float* Wc     = (const float*)d_in[23];
  const float* bc     = (const float*)d_in[24];
  const float* g_out  = (const float*)d_in[25];
  const float* b_out  = (const float*)d_in[26];
  float* out = (float*)d_out;

  // ---- workspace layout: PEAK ~229.4 MB (< 235.88 MB proven safe) ----
  char* ws = (char*)d_ws;
  bf16* rel_cat = (bf16*)ws;                         // [N][1536] bf16 = 153,600,000
  char* W0 = ws + 153600000;                         // weights: 5,058,560
  bf16*  Wqt   = (bf16*)(W0 + 0);          // [1536][256]   (6 relations stacked on NC)
  bf16*  Wkvt  = (bf16*)(W0 + 786432);     // [6][512][320] (k rows 0..255, v rows 256..511)
  bf16*  Wmt   = (bf16*)(W0 + 2752512);    // [6][256][256]
  bf16*  Wir1t = (bf16*)(W0 + 3538944);    // [256][1536]
  bf16*  Wct   = (bf16*)(W0 + 4325376);    // [256][512]
  bf16*  Wmpt  = (bf16*)(W0 + 4587520);    // [3][256][256]
  bf16*  Wa1t  = (bf16*)(W0 + 4980736);    // [128][256]
  float* bkv   = (float*)(W0 + 5046272);   // [6][512] fp32 (end 5,058,560)
  char* region = ws + 158658560;
  // phase-1 views
  bf16*     kvbuf = (bf16*)(region + 0);             // [E][512] bf16 = 33,554,432
  float*    denom = (float*)(region + 33554432);     //  1,600,000
  bf16*     xb    = (bf16*)(region + 38851584);      // [N][256] bf16 = 25,600,000 (end 64,451,584)
  bf16*     eab   = (bf16*)(region + 64451584);      // [6][E][16] bf16 = 6,291,456 (end 70,743,040)
  bf16*     zpad  = (bf16*)(region + 70743040);      // 64 B zeroed (gl2lds pad source)
  float*    agg   = out;                             // d_out as fp32 accumulator (phase 1)
  // phase-2 overlay (kvbuf dead)
  bf16*  hbuf     = (bf16*)(region + 0);             // 25,600,000
  float* interw   = (float*)(region + 33554432);     //  1,200,000 (denom dead)
  // phase-3 overlay (hbuf/interw/xb dead)
  bf16*  tmp      = (bf16*)(region + 0);             // [2][N][256] = 51,200,000
  float* logits   = (float*)(region + 51200000);     //    600,000 (end 51,800,000)
  // phase-5
  bf16*  comb     = (bf16*)out;                      // [N][512] bf16 in d_out
  float* combined = (float*)(region + 0);            // [N][256] fp32 (tmp dead; logits above)

  // grids: x = col tiles, y = row tiles (A-tile L2 reuse across x)
  const dim3 gN(2, 391);     // M=50000, NC=256
  const dim3 gQ(12, 391);    // M=50000, NC=1536 (batched q)
  const dim3 gKV(4, 256);    // M=32768, NC=512 (k||v)
  const dim3 gMP2(2, 391, 2);// metapath batch z=0,1
  const dim3 gMP1(2, 391, 1);// metapath batch z=2
  const dim3 gL(1, 391, 3);  // M=50000, NC=128, z=3 meta-paths (logits)

  // ---- phase 0: weight transpose/convert + x->bf16 + eattr->bf16 ----
  tconv_k<<<dim3(8, 8, 6), 256, 0, stream>>>(Wq, Wqt, 256, 256, 256, 256 * 256, 256 * 256);
  tconv_k<<<dim3(10, 8, 6), 256, 0, stream>>>(Wk, Wkvt, 272, 256, 320, 272 * 256, 512 * 320);
  tconv_k<<<dim3(10, 8, 6), 256, 0, stream>>>(Wv, Wkvt + 256 * 320, 272, 256, 320, 272 * 256, 512 * 320);
  tconv_k<<<dim3(8, 8, 6), 256, 0, stream>>>(Wm, Wmt, 256, 256, 256, 256 * 256, 256 * 256);
  tconv_k<<<dim3(48, 8, 1), 256, 0, stream>>>(W_ir1, Wir1t, 1536, 256, 1536, 0, 0);
  tconv_k<<<dim3(16, 8, 1), 256, 0, stream>>>(Wc, Wct, 512, 256, 512, 0, 0);
  tconv_k<<<dim3(8, 8, 3), 256, 0, stream>>>(Wmp, Wmpt, 256, 256, 256, 256 * 256, 256 * 256);
  tconv_k<<<dim3(8, 4, 1), 256, 0, stream>>>(Wa1, Wa1t, 256, 128, 256, 0, 0);
  bkv_k<<<12, 256, 0, stream>>>(bk, bv, bkv);
  cvt_k<<<(NN * 64 + 255) / 256, 256, 0, stream>>>(x, xb, NN * 64);
  cvt_k<<<(RR * EE * FF / 4 + 255) / 256, 256, 0, stream>>>(eattr, eab, RR * EE * FF / 4);
  zero_k<<<1, 256, 0, stream>>>((uint4*)zpad, 4);

  // ---- phase 1a: ALL q in one GEMM (bf16 A, gl2lds pipeline) -> rel_cat.
  // Slot r is consumed by edge_k(r) BEFORE the Wm GEMM overwrites it. ----
  mm_k<0, 0, 0, bf16><<<gQ, 256, 0, stream>>>(
      xb, nullptr, 256, nullptr, nullptr, nullptr,
      Wqt, bq, nullptr, rel_cat, 1536, nullptr, NN, 256, 0);

  // ---- phase 1b: per-relation attention (fused edge pass, no segment-max) ----
  for (int r = 0; r < RR; ++r) {
    const int* src = eidx + (size_t)r * 2 * EE;
    const int* dst = src + EE;
    zero_k<<<98, 256, 0, stream>>>((uint4*)denom, (NN * NHEAD * 4) / 16);
    zero_k<<<2048, 256, 0, stream>>>((uint4*)agg, (NN * HH * 4) / 16);
    // k||v = [xb[src]||eab||0] @ Wkv[r] (pure gl2lds gather; zpad via dnm arg)
    mm_k<3, 0, 0, bf16><<<gKV, 256, 0, stream>>>(
        xb, nullptr, 0, src, eab + (size_t)r * EE * FF, (const float*)zpad,
        Wkvt + (size_t)r * 512 * KVP, bkv + r * 512, nullptr, kvbuf, 512, nullptr, EE, KVP, 0);
    // fused scores+exp+aggregate (unnormalized): denom & agg accumulate
    edge_k<<<EE, 256, 0, stream>>>(rel_cat + r * 256, kvbuf, dst, prior + r * NHEAD, denom, agg);
    // rel[r] = gelu((agg/denom) @ Wm[r] + bm[r]) -> rel_cat slot r
    mm_k<4, 1, 0, bf16><<<gN, 256, 0, stream>>>(
        agg, nullptr, 256, nullptr, nullptr, denom,
        Wmt + (size_t)r * 256 * 256, bm + r * HH, nullptr,
        rel_cat + r * 256, 1536, nullptr, NN, 256, 0);
  }

  // ---- phase 2: inter-relation chain (consumes rel_cat BEFORE meta overwrites) ----
  mm_k<0, 1, 0, bf16><<<gN, 256, 0, stream>>>(
      rel_cat, nullptr, 1536, nullptr, nullptr, nullptr,
      Wir1t, b_ir1, nullptr, hbuf, 256, nullptr, NN, 1536, 0);
  interw_k<<<(NN + 3) / 4, 256, 0, stream>>>(hbuf, W_ir2, b_ir2, interw);
  interagg_k<<<NN, 256, 0, stream>>>(interw, rel_cat, comb);

  // ---- phase 3: meta-path chain (z-batched into tmp, then copy to slots) ----
  mm_k<2, 0, 3, bf16><<<gMP2, 256, 0, stream>>>(
      rel_cat, rel_cat, 1536, nullptr, nullptr, nullptr,
      Wmpt, bmp, nullptr, tmp, 256, nullptr, NN, 256, 0);
  copyslot_k<<<(NN * 32 + 255) / 256, 256, 0, stream>>>(tmp, rel_cat + 2 * 256);
  copyslot_k<<<(NN * 32 + 255) / 256, 256, 0, stream>>>(tmp + (size_t)NN * 256, rel_cat + 4 * 256);
  mm_k<2, 0, 3, bf16><<<gMP1, 256, 0, stream>>>(
      rel_cat, rel_cat, 1536, nullptr, nullptr, nullptr,
      Wmpt, bmp, nullptr, tmp, 256, nullptr, NN, 256, 2);
  copyslot_k<<<(NN * 32 + 255) / 256, 256, 0, stream>>>(tmp, rel_cat + 1 * 256);

  zero_k<<<147, 256, 0, stream>>>((uint4*)logits, (3 * NN * 4) / 16);
  // logits[z] = sum_i tanh(stacked[z] @ Wa1 + ba1)_i * Wa2_i  (z=3 batched)
  mm_k<0, 0, 1, bf16><<<gL, 256, 0, stream>>>(
      rel_cat, nullptr, 1536, nullptr, nullptr, nullptr,
      Wa1t, ba1, Wa2, (bf16*)nullptr, 0, logits, NN, 256, 0);
  metafinal_k<<<(NN + 3) / 4, 256, 0, stream>>>(logits, rel_cat, g_meta, b_meta, comb);

  // ---- phase 4: combine + output LN (d_out) ----
  mm_k<0, 1, 0, float><<<gN, 256, 0, stream>>>(
      comb, nullptr, 512, nullptr, nullptr, nullptr,
      Wct, bc, nullptr, combined, 256, nullptr, NN, 512, 0);
  final_k<<<NN, 256, 0, stream>>>(x, combined, g_out, b_out, out);
}

// Round 7
// 1457.954 us; speedup vs baseline: 1.0188x; 1.0188x over previous
//
#include <hip/hip_runtime.h>
#include <hip/hip_bf16.h>

typedef __hip_bfloat16 bf16;
typedef __attribute__((ext_vector_type(8))) short short8;
typedef __attribute__((ext_vector_type(4))) float f32x4;

#define NN 50000
#define RR 6
#define EE 32768
#define HH 256
#define FF 16
#define NHEAD 8
#define KVP 320   // 272 padded to multiple of 64

struct __align__(8) bf16x4 { bf16 v[4]; };

__device__ __forceinline__ float b2f(bf16 v) { return __bfloat162float(v); }
__device__ __forceinline__ bf16 f2b(float v) { return __float2bfloat16(v); }
__device__ __forceinline__ short f2s(float f) { bf16 b = f2b(f); return __builtin_bit_cast(short, b); }
__device__ __forceinline__ float s2f(short s) { return b2f(__builtin_bit_cast(bf16, s)); }
__device__ __forceinline__ float gelu_f(float x) { return 0.5f * x * (1.0f + erff(x * 0.7071067811865476f)); }

// async global->LDS, 16B per lane (dest = wave-uniform base + lane*16;
// the GLOBAL address may be fully per-lane -> gather-capable)
__device__ __forceinline__ void gl2lds16(const void* g, void* l) {
  __builtin_amdgcn_global_load_lds(
      (const __attribute__((address_space(1))) unsigned int*)g,
      (__attribute__((address_space(3))) unsigned int*)l, 16, 0, 0);
}

// grid-stride zero fill (16B granules)
__global__ void zero_k(uint4* __restrict__ p, int n16)
{
  const uint4 z = make_uint4(0u, 0u, 0u, 0u);
  for (int i = blockIdx.x * blockDim.x + threadIdx.x; i < n16; i += gridDim.x * blockDim.x)
    p[i] = z;
}

// fp32 -> bf16 elementwise (4 per thread)
__global__ void cvt_k(const float* __restrict__ in, bf16* __restrict__ out, int n4)
{
  const int i = blockIdx.x * 256 + threadIdx.x;
  if (i >= n4) return;
  const float4 f = ((const float4*)in)[i];
  bf16x4 o; o.v[0] = f2b(f.x); o.v[1] = f2b(f.y); o.v[2] = f2b(f.z); o.v[3] = f2b(f.w);
  ((bf16x4*)out)[i] = o;
}

// transpose-convert: in fp32 [K][NC] -> out bf16 [NC][Kp], zero-pad K..Kp.
__global__ void tconv_k(const float* __restrict__ in, bf16* __restrict__ out,
                        int K, int NC, int Kp, long izs, long ozs)
{
  __shared__ float t[32][33];
  in  += (size_t)blockIdx.z * izs;
  out += (size_t)blockIdx.z * ozs;
  const int kb = blockIdx.x * 32, nb = blockIdx.y * 32;
  const int tx = threadIdx.x & 31, ty = threadIdx.x >> 5;  // ty 0..7
  for (int i = ty; i < 32; i += 8) {
    const int k = kb + i, n = nb + tx;
    t[i][tx] = (k < K && n < NC) ? in[(size_t)k * NC + n] : 0.f;
  }
  __syncthreads();
  for (int i = ty; i < 32; i += 8) {
    const int n = nb + i, k = kb + tx;
    if (n < NC && k < Kp) out[(size_t)n * Kp + k] = f2b(t[tx][i]);
  }
}

// build concatenated kv bias: bkv[r][0..255]=bk[r], bkv[r][256..511]=bv[r]
__global__ void bkv_k(const float* __restrict__ bk, const float* __restrict__ bv,
                      float* __restrict__ bkv)
{
  const int i = blockIdx.x * 256 + threadIdx.x;
  if (i >= RR * 512) return;
  const int r = i >> 9, c = i & 511;
  bkv[i] = (c < 256) ? bk[r * 256 + c] : bv[r * 256 + (c - 256)];
}

// copy tmp [N][256] bf16 -> rel_cat slot (ld 1536)
__global__ void copyslot_k(const bf16* __restrict__ tmp, bf16* __restrict__ slot)
{
  const int i = blockIdx.x * 256 + threadIdx.x;  // 8-elem chunk id
  if (i >= NN * 32) return;
  const int n = i >> 5, c = (i & 31) * 8;
  *(short8*)(slot + (size_t)n * 1536 + c) = *(const short8*)(tmp + (size_t)n * 256 + c);
}

// ---------------------------------------------------------------------------
// MFMA GEMM (round-5 proven 1-phase, 32KB LDS, ~3 blocks/CU):
// C[M,NC] = act(A[M,K] @ Bt^T + bias), Bt = [NC][K] bf16 k-contig.
// 128x128 tile, BK=64, 4 waves, each wave 64x64 (4x4 of 16x16x32 MFMA).
// LDS chunk (row, cg) holds global chunk cg ^ (row&7) (bank swizzle, staging
// stays lane-contiguous / gl2lds-legal).
// ASRC: 0=A bf16 async; 2=PAIR bf16 sum (reg-staged); 3=KV gather reg-staged
//       (xb[src[r]] bf16 | eab bf16 | zero pad); 4=A fp32 scaled by
//       1/(dnm[row,head]+1e-16) (softmax-normalize fused into staging).
// ZMODE: 0=plain; 1=logits (A = rel_cat+slot3[z]*256, epilogue
//        atomicAdd(logits[z*M+row], sum tanh(c+bias)*wa2));
//        3=metapath batch (z picks pair slots + B/bias, C += z*M*256);
//        4=KV-FUSED (z = relation pair member): A = kv gather; col-tiles 0/1
//        hold k heads -> epilogue gathers q[dst[e]] into LDS, dots against
//        the fp32 acc (+bias), shuffle-reduces 16 lanes, writes
//        ex=exp(s*scale*prior) and atomicAdds denom — k NEVER materialized
//        (closer to fp32 reference than the old bf16 k round-trip).
//        Col-tiles 2/3 write v to kvbuf [E][256]. logits param = ex||denom
//        region: ex=[2][E][8] then denom=[2][N][8] (fp32).
// ---------------------------------------------------------------------------
template<int ASRC, int ACT, int ZMODE, typename TO>
__global__ __launch_bounds__(256) void mm_k(
    const void* __restrict__ Av, const bf16* __restrict__ A2, int lda,
    const int* __restrict__ src, const bf16* __restrict__ eab,
    const float* __restrict__ dnm,
    const bf16* __restrict__ Bt, const float* __restrict__ bias,
    const float* __restrict__ wa2, TO* __restrict__ C, int ldc,
    float* __restrict__ logits, int M, int K, int z0)
{
  __shared__ short lds[2 * 128 * 64];   // lA = lds[0..8191], lB = lds[8192..]
  const int tid = threadIdx.x;
  const int w = tid >> 6, l = tid & 63;
  const int col0 = blockIdx.x << 7;
  const int row0 = blockIdx.y << 7;
  const bf16* Ab = (const bf16*)Av;
  const bf16* A2b = A2;
  const bf16* Btz = Bt;
  const float* biasz = bias;
  TO* Cz = C;
  float* lg = logits;
  const int* srcz = src;
  const int* dstz = nullptr;
  const bf16* eabz = eab;
  const bf16* qz = nullptr;
  float* exbz = nullptr;
  float* dnmaz = nullptr;
  const float* priz = nullptr;
  if constexpr (ZMODE == 1) {
    const int slots3[3] = {2, 4, 1};
    Ab = (const bf16*)Av + slots3[blockIdx.z] * 256;
    lg = logits + (size_t)blockIdx.z * M;
  } else if constexpr (ZMODE == 3) {
    const int r1s[3] = {2, 4, 1}, r2s[3] = {3, 0, 5};
    const int z = blockIdx.z + z0;
    Ab  = (const bf16*)Av + (size_t)r1s[z] * 256;
    A2b = A2 + (size_t)r2s[z] * 256;
    Btz = Bt + (size_t)z * 256 * K;
    biasz = bias + z * 256;
    Cz = C + (size_t)blockIdx.z * (size_t)M * 256;
  } else if constexpr (ZMODE == 4) {
    const int z = blockIdx.z;
    srcz  = src + (size_t)z * 2 * EE;
    dstz  = srcz + EE;
    eabz  = eab + (size_t)z * EE * FF;
    qz    = A2 + z * 256;                 // rel_cat q slot (row stride 1536)
    Btz   = Bt + (size_t)z * 512 * KVP;
    biasz = bias + z * 512;
    Cz    = C + (size_t)z * (size_t)EE * 256;
    exbz  = logits + (size_t)z * EE * NHEAD;
    dnmaz = logits + (size_t)2 * EE * NHEAD + (size_t)z * NN * NHEAD;
    priz  = dnm + z * NHEAD;
  }
  const int wm = (w >> 1) << 6, wn = (w & 1) << 6;
  const int lane15 = l & 15, kq = l >> 4;

  f32x4 acc[4][4] = {};

  for (int k0 = 0; k0 < K; k0 += 64) {
    // stage A tile [128][64] (swizzled chunks)
#pragma unroll
    for (int i = 0; i < 4; ++i) {
      const int idx = (w * 4 + i) * 64 + l;        // 0..1023 16B chunks
      const int row = idx >> 3, cg = idx & 7;
      const int scg = cg ^ (row & 7);
      const int r = min(row0 + row, M - 1);
      const int kc = k0 + scg * 8;
      if constexpr (ASRC == 0) {
        gl2lds16(Ab + (size_t)r * lda + kc, &lds[idx * 8]);
      } else if constexpr (ASRC == 2) {
        const short8 u  = *(const short8*)(Ab  + (size_t)r * lda + kc);
        const short8 v2 = *(const short8*)(A2b + (size_t)r * lda + kc);
        short8 s;
#pragma unroll
        for (int j = 0; j < 8; ++j) s[j] = f2s(s2f(u[j]) + s2f(v2[j]));
        *(short8*)&lds[idx * 8] = s;
      } else if constexpr (ASRC == 3) {  // kv gather: xb bf16 | eab bf16 | pad
        short8 s;
        if (kc < HH) {
          s = *(const short8*)((const bf16*)Av + (size_t)srcz[r] * HH + kc);
        } else if (kc < HH + FF) {
          s = *(const short8*)(eabz + (size_t)r * FF + (kc - HH));
        } else {
#pragma unroll
          for (int j = 0; j < 8; ++j) s[j] = 0;
        }
        *(short8*)&lds[idx * 8] = s;
      } else {  // ASRC == 4: fp32 agg scaled by 1/(denom+1e-16), chunk in one head
        const float* p = (const float*)Av + (size_t)r * lda + kc;
        const float4 f0 = *(const float4*)p;
        const float4 f1 = *(const float4*)(p + 4);
        const float iv = 1.0f / (dnm[r * NHEAD + (kc >> 5)] + 1e-16f);
        short8 s;
        s[0] = f2s(f0.x * iv); s[1] = f2s(f0.y * iv); s[2] = f2s(f0.z * iv); s[3] = f2s(f0.w * iv);
        s[4] = f2s(f1.x * iv); s[5] = f2s(f1.y * iv); s[6] = f2s(f1.z * iv); s[7] = f2s(f1.w * iv);
        *(short8*)&lds[idx * 8] = s;
      }
    }
    // stage B tile [128][64] (swizzled, async; block's 128 cols always in range)
#pragma unroll
    for (int i = 0; i < 4; ++i) {
      const int idx = (w * 4 + i) * 64 + l;
      const int row = idx >> 3, cg = idx & 7;
      const int scg = cg ^ (row & 7);
      gl2lds16(Btz + (size_t)(col0 + row) * K + k0 + scg * 8, &lds[8192 + idx * 8]);
    }
    __syncthreads();
#pragma unroll
    for (int kk = 0; kk < 64; kk += 32) {
      short8 af[4], bfr[4];
#pragma unroll
      for (int t = 0; t < 4; ++t) {
        const int ra = wm + t * 16 + lane15;
        const int ca = ((kk >> 3) + kq) ^ (ra & 7);
        af[t] = *(const short8*)&lds[ra * 64 + ca * 8];
        const int rb = wn + t * 16 + lane15;
        const int cb = ((kk >> 3) + kq) ^ (rb & 7);
        bfr[t] = *(const short8*)&lds[8192 + rb * 64 + cb * 8];
      }
#pragma unroll
      for (int ti = 0; ti < 4; ++ti)
#pragma unroll
        for (int tj = 0; tj < 4; ++tj)
          acc[ti][tj] = __builtin_amdgcn_mfma_f32_16x16x32_bf16(af[ti], bfr[tj], acc[ti][tj], 0, 0, 0);
    }
    __syncthreads();
  }

  if constexpr (ZMODE == 4) {
    if (blockIdx.x < 2) {
      // ---- scores epilogue: gather q[dst[e]][col0..col0+127] into 32KB LDS ----
#pragma unroll
      for (int i = 0; i < 8; ++i) {
        const int idx = (w * 8 + i) * 64 + l;     // 0..2047 16B chunks
        const int row = idx >> 4, cg = idx & 15;  // 16 chunks per 128-col row
        const int d = dstz[row0 + row];
        gl2lds16(qz + (size_t)d * 1536 + col0 + cg * 8, &lds[idx * 8]);
      }
      __syncthreads();   // drains vmcnt(0) for gl2lds
      const int hb = (col0 + wn) >> 5;            // head of tj=0,1; tj=2,3 -> hb+1
      const float pr0 = priz[hb], pr1 = priz[hb + 1];
#pragma unroll
      for (int ti = 0; ti < 4; ++ti) {
#pragma unroll
        for (int reg = 0; reg < 4; ++reg) {
          const int row = wm + ti * 16 + kq * 4 + reg;   // local row (edge)
          float p0 = 0.f, p1 = 0.f;
#pragma unroll
          for (int tj = 0; tj < 4; ++tj) {
            const int colL = wn + tj * 16 + lane15;      // local col 0..127
            const float kv_ = acc[ti][tj][reg] + biasz[col0 + colL];  // fp32 k
            const float qv = s2f(lds[(row << 7) + colL]);
            if (tj < 2) p0 += qv * kv_; else p1 += qv * kv_;
          }
#pragma unroll
          for (int off = 1; off < 16; off <<= 1) {
            p0 += __shfl_xor(p0, off, 64);
            p1 += __shfl_xor(p1, off, 64);
          }
          if (lane15 == 0) {
            const int e = row0 + row;
            const int d = dstz[e];
            const float e0 = expf(p0 * 0.1767766952966369f * pr0);
            const float e1 = expf(p1 * 0.1767766952966369f * pr1);
            exbz[e * NHEAD + hb]     = e0;
            exbz[e * NHEAD + hb + 1] = e1;
            atomicAdd(&dnmaz[d * NHEAD + hb],     e0);
            atomicAdd(&dnmaz[d * NHEAD + hb + 1], e1);
          }
        }
      }
    } else {
      // ---- v half: write kvbuf [E][256] bf16 ----
#pragma unroll
      for (int ti = 0; ti < 4; ++ti) {
#pragma unroll
        for (int reg = 0; reg < 4; ++reg) {
          const int row = row0 + wm + ti * 16 + kq * 4 + reg;
#pragma unroll
          for (int tj = 0; tj < 4; ++tj) {
            const int col = col0 + wn + tj * 16 + lane15;   // 256..511
            const float v = acc[ti][tj][reg] + biasz[col];
            Cz[(size_t)row * 256 + (col - 256)] = (TO)f2b(v);
          }
        }
      }
    }
  } else if constexpr (ZMODE != 1) {
    // C layout: col = lane&15, row = (lane>>4)*4 + reg  [m89-verified]
#pragma unroll
    for (int ti = 0; ti < 4; ++ti) {
#pragma unroll
      for (int reg = 0; reg < 4; ++reg) {
        const int row = row0 + wm + ti * 16 + kq * 4 + reg;
        if (row >= M) continue;
#pragma unroll
        for (int tj = 0; tj < 4; ++tj) {
          const int col = col0 + wn + tj * 16 + lane15;
          float v = acc[ti][tj][reg] + biasz[col];
          if constexpr (ACT == 1) v = gelu_f(v);
          if constexpr (sizeof(TO) == 2) Cz[(size_t)row * ldc + col] = (TO)f2b(v);
          else                           Cz[(size_t)row * ldc + col] = (TO)v;
        }
      }
    }
  } else {
#pragma unroll
    for (int ti = 0; ti < 4; ++ti) {
#pragma unroll
      for (int reg = 0; reg < 4; ++reg) {
        float part = 0.f;
#pragma unroll
        for (int tj = 0; tj < 4; ++tj) {
          const int col = col0 + wn + tj * 16 + lane15;
          part += tanhf(acc[ti][tj][reg] + biasz[col]) * wa2[col];
        }
#pragma unroll
        for (int off = 8; off > 0; off >>= 1) part += __shfl_xor(part, off, 64);
        const int row = row0 + wm + ti * 16 + kq * 4 + reg;
        if (lane15 == 0 && row < M) atomicAdd(&lg[row], part);
      }
    }
  }
}

// ---------------------------------------------------------------------------
// v-aggregate pass: w = ex[e,h]; agg[dst,:] += w * v[e,:] (contig atomics).
// scores/exp/denom already done in the kv GEMM epilogue.
// ---------------------------------------------------------------------------
__global__ void edge2_k(const float* __restrict__ ex, const bf16* __restrict__ v,
                        const int* __restrict__ dst_idx, float* __restrict__ agg)
{
  const int e = blockIdx.x, t = threadIdx.x;
  const int dst = dst_idx[e];
  const float w = ex[e * NHEAD + (t >> 5)];
  atomicAdd(&agg[(size_t)dst * HH + t], w * b2f(v[(size_t)e * HH + t]));
}

// ---------------------------------------------------------------------------
// inter-relation softmax weights; one wave per node
// ---------------------------------------------------------------------------
__global__ void interw_k(const bf16* __restrict__ h, const float* __restrict__ W2,
                         const float* __restrict__ b2, float* __restrict__ interw)
{
  const int wv = threadIdx.x >> 6, ln = threadIdx.x & 63;
  const int n = blockIdx.x * 4 + wv;
  if (n >= NN) return;
  float a[6] = {0.f, 0.f, 0.f, 0.f, 0.f, 0.f};
#pragma unroll
  for (int kq = 0; kq < 4; ++kq) {
    const int k = ln + (kq << 6);
    const float hv = b2f(h[(size_t)n * HH + k]);
#pragma unroll
    for (int j = 0; j < 6; ++j) a[j] += hv * W2[k * 6 + j];
  }
#pragma unroll
  for (int j = 0; j < 6; ++j) {
#pragma unroll
    for (int off = 32; off > 0; off >>= 1) a[j] += __shfl_down(a[j], off, 64);
  }
  if (ln == 0) {
    float lg[6], e[6], mx = -1e30f, s = 0.f;
#pragma unroll
    for (int j = 0; j < 6; ++j) { lg[j] = a[j] + b2[j]; mx = fmaxf(mx, lg[j]); }
#pragma unroll
    for (int j = 0; j < 6; ++j) { e[j] = expf(lg[j] - mx); s += e[j]; }
    const float inv = 1.0f / s;
#pragma unroll
    for (int j = 0; j < 6; ++j) interw[(size_t)n * 6 + j] = e[j] * inv;
  }
}

// rel_cat layout: [N][R*256]
__global__ void interagg_k(const float* __restrict__ interw, const bf16* __restrict__ rel_cat,
                           bf16* __restrict__ comb)
{
  const int n = blockIdx.x, t = threadIdx.x;
  float acc = 0.f;
#pragma unroll
  for (int r = 0; r < 6; ++r)
    acc += interw[(size_t)n * 6 + r] * b2f(rel_cat[(size_t)n * 1536 + r * 256 + t]);
  comb[(size_t)n * 512 + t] = f2b(acc);
}

// ---------------------------------------------------------------------------
// meta final: softmax(logits[3]) -> weighted sum of stacked -> LN -> comb[:,256:]
// ---------------------------------------------------------------------------
__global__ void metafinal_k(const float* __restrict__ logits, const bf16* __restrict__ rel_cat,
                            const float* __restrict__ gmeta, const float* __restrict__ bmeta,
                            bf16* __restrict__ comb)
{
  const int wv = threadIdx.x >> 6, ln = threadIdx.x & 63;
  const int n = blockIdx.x * 4 + wv;
  if (n >= NN) return;
  const float l0 = logits[n], l1 = logits[NN + n], l2 = logits[2 * NN + n];
  const float mx = fmaxf(l0, fmaxf(l1, l2));
  const float e0 = expf(l0 - mx), e1 = expf(l1 - mx), e2 = expf(l2 - mx);
  const float inv = 1.0f / (e0 + e1 + e2);
  const float a0 = e0 * inv, a1 = e1 * inv, a2 = e2 * inv;
  const size_t base = (size_t)n * 1536;
  float pre[4], s = 0.f, s2 = 0.f;
#pragma unroll
  for (int q4 = 0; q4 < 4; ++q4) {
    const int j = ln + (q4 << 6);
    const float v = a0 * b2f(rel_cat[base + 2 * 256 + j])
                  + a1 * b2f(rel_cat[base + 4 * 256 + j])
                  + a2 * b2f(rel_cat[base + 1 * 256 + j]);
    pre[q4] = v; s += v; s2 += v * v;
  }
#pragma unroll
  for (int off = 32; off > 0; off >>= 1) { s += __shfl_down(s, off, 64); s2 += __shfl_down(s2, off, 64); }
  s = __shfl(s, 0, 64); s2 = __shfl(s2, 0, 64);
  const float mu = s * (1.0f / 256.0f);
  const float var = s2 * (1.0f / 256.0f) - mu * mu;
  const float rs = rsqrtf(var + 1e-5f);
#pragma unroll
  for (int q4 = 0; q4 < 4; ++q4) {
    const int j = ln + (q4 << 6);
    comb[(size_t)n * 512 + 256 + j] = f2b((pre[q4] - mu) * rs * gmeta[j] + bmeta[j]);
  }
}

// final: out = LN(x + combined)
__global__ void final_k(const float* __restrict__ x, const float* __restrict__ combined,
                        const float* __restrict__ g, const float* __restrict__ b,
                        float* __restrict__ out)
{
  __shared__ float sred[8];
  const int n = blockIdx.x, t = threadIdx.x;
  const float v = x[(size_t)n * HH + t] + combined[(size_t)n * HH + t];
  float s = v, s2 = v * v;
#pragma unroll
  for (int off = 32; off > 0; off >>= 1) { s += __shfl_down(s, off, 64); s2 += __shfl_down(s2, off, 64); }
  const int wv = t >> 6;
  if ((t & 63) == 0) { sred[wv] = s; sred[4 + wv] = s2; }
  __syncthreads();
  const float st = sred[0] + sred[1] + sred[2] + sred[3];
  const float st2 = sred[4] + sred[5] + sred[6] + sred[7];
  const float mu = st * (1.0f / 256.0f);
  const float var = st2 * (1.0f / 256.0f) - mu * mu;
  const float rs = rsqrtf(var + 1e-5f);
  out[(size_t)n * HH + t] = (v - mu) * rs * g[t] + b[t];
}

// ---------------------------------------------------------------------------
extern "C" void kernel_launch(void* const* d_in, const int* in_sizes, int n_in,
                              void* d_out, int out_size, void* d_ws, size_t ws_size,
                              hipStream_t stream)
{
  const float* x      = (const float*)d_in[0];
  const int*   eidx   = (const int*)d_in[1];
  const float* eattr  = (const float*)d_in[2];
  const float* Wq     = (const float*)d_in[3];
  const float* bq     = (const float*)d_in[4];
  const float* Wk     = (const float*)d_in[5];
  const float* bk     = (const float*)d_in[6];
  const float* Wv     = (const float*)d_in[7];
  const float* bv     = (const float*)d_in[8];
  const float* prior  = (const float*)d_in[9];
  const float* Wm     = (const float*)d_in[10];
  const float* bm     = (const float*)d_in[11];
  const float* W_ir1  = (const float*)d_in[12];
  const float* b_ir1  = (const float*)d_in[13];
  const float* W_ir2  = (const float*)d_in[14];
  const float* b_ir2  = (const float*)d_in[15];
  const float* Wmp    = (const float*)d_in[16];
  const float* bmp    = (const float*)d_in[17];
  const float* Wa1    = (const float*)d_in[18];
  const float* ba1    = (const float*)d_in[19];
  const float* Wa2    = (const float*)d_in[20];
  const float* g_meta = (const float*)d_in[21];
  const float* b_meta = (const float*)d_in[22];
  const float* Wc     = (const float*)d_in[23];
  const float* bc     = (const float*)d_in[24];
  const float* g_out  = (const float*)d_in[25];
  const float* b_out  = (const float*)d_in[26];
  float* out = (float*)d_out;

  // ---- workspace layout: PEAK ~229.4 MB (< 235.88 MB proven safe) ----
  char* ws = (char*)d_ws;
  bf16* rel_cat = (bf16*)ws;                         // [N][1536] bf16 = 153,600,000
  char* W0 = ws + 153600000;                         // weights: 5,058,560
  bf16*  Wqt   = (bf16*)(W0 + 0);          // [1536][256]   (6 relations stacked on NC)
  bf16*  Wkvt  = (bf16*)(W0 + 786432);     // [6][512][320] (k rows 0..255, v rows 256..511)
  bf16*  Wmt   = (bf16*)(W0 + 2752512);    // [6][256][256]
  bf16*  Wir1t = (bf16*)(W0 + 3538944);    // [256][1536]
  bf16*  Wct   = (bf16*)(W0 + 4325376);    // [256][512]
  bf16*  Wmpt  = (bf16*)(W0 + 4587520);    // [3][256][256]
  bf16*  Wa1t  = (bf16*)(W0 + 4980736);    // [128][256]
  float* bkv   = (float*)(W0 + 5046272);   // [6][512] fp32 (end 5,058,560)
  char* region = ws + 158658560;
  // phase-1 views (relation PAIRS)
  bf16*  kvbuf  = (bf16*)(region + 0);               // [2][E][256] v-only = 33,554,432
  float* exden  = (float*)(region + 33554432);       // ex [2][E][8] = 2,097,152
  float* denom2 = exden + 2 * EE * NHEAD;            // denom [2][N][8] = 3,200,000 (end 38,851,584)
  bf16*  xb     = (bf16*)(region + 38851584);        // [N][256] bf16 = 25,600,000 (end 64,451,584)
  bf16*  eab    = (bf16*)(region + 64451584);        // [6][E][16] bf16 = 6,291,456 (end 70,743,040)
  float* agg    = out;                               // d_out as fp32 accumulator (phase 1)
  // phase-2 overlay (kvbuf dead)
  bf16*  hbuf     = (bf16*)(region + 0);             // 25,600,000
  float* interw   = (float*)(region + 33554432);     //  1,200,000 (exden dead)
  // phase-3 overlay (hbuf/interw/xb dead)
  bf16*  tmp      = (bf16*)(region + 0);             // [2][N][256] = 51,200,000
  float* logits   = (float*)(region + 51200000);     //    600,000 (end 51,800,000)
  // phase-5
  bf16*  comb     = (bf16*)out;                      // [N][512] bf16 in d_out
  float* combined = (float*)(region + 0);            // [N][256] fp32 (tmp dead; logits above)

  // grids: x = col tiles, y = row tiles (A-tile L2 reuse across x)
  const dim3 gN(2, 391);       // M=50000, NC=256
  const dim3 gQ(12, 391);      // M=50000, NC=1536 (batched q)
  const dim3 gKV(4, 256, 2);   // M=32768, NC=512, z=relation pair (kv fused)
  const dim3 gMP2(2, 391, 2);  // metapath batch z=0,1
  const dim3 gMP1(2, 391, 1);  // metapath batch z=2
  const dim3 gL(1, 391, 3);    // M=50000, NC=128, z=3 meta-paths (logits)

  // ---- phase 0: weight transpose/convert + x->bf16 + eattr->bf16 ----
  tconv_k<<<dim3(8, 8, 6), 256, 0, stream>>>(Wq, Wqt, 256, 256, 256, 256 * 256, 256 * 256);
  tconv_k<<<dim3(10, 8, 6), 256, 0, stream>>>(Wk, Wkvt, 272, 256, 320, 272 * 256, 512 * 320);
  tconv_k<<<dim3(10, 8, 6), 256, 0, stream>>>(Wv, Wkvt + 256 * 320, 272, 256, 320, 272 * 256, 512 * 320);
  tconv_k<<<dim3(8, 8, 6), 256, 0, stream>>>(Wm, Wmt, 256, 256, 256, 256 * 256, 256 * 256);
  tconv_k<<<dim3(48, 8, 1), 256, 0, stream>>>(W_ir1, Wir1t, 1536, 256, 1536, 0, 0);
  tconv_k<<<dim3(16, 8, 1), 256, 0, stream>>>(Wc, Wct, 512, 256, 512, 0, 0);
  tconv_k<<<dim3(8, 8, 3), 256, 0, stream>>>(Wmp, Wmpt, 256, 256, 256, 256 * 256, 256 * 256);
  tconv_k<<<dim3(8, 4, 1), 256, 0, stream>>>(Wa1, Wa1t, 256, 128, 256, 0, 0);
  bkv_k<<<12, 256, 0, stream>>>(bk, bv, bkv);
  cvt_k<<<(NN * 64 + 255) / 256, 256, 0, stream>>>(x, xb, NN * 64);
  cvt_k<<<(RR * EE * FF / 4 + 255) / 256, 256, 0, stream>>>(eattr, eab, RR * EE * FF / 4);

  // ---- phase 1a: ALL q in one GEMM (bf16 A, pure async staging) -> rel_cat.
  // Slot r is consumed by the kv-fused GEMM epilogue BEFORE Wm overwrites it. ----
  mm_k<0, 0, 0, bf16><<<gQ, 256, 0, stream>>>(
      xb, nullptr, 256, nullptr, nullptr, nullptr,
      Wqt, bq, nullptr, rel_cat, 1536, nullptr, NN, 256, 0);

  // ---- phase 1b: per-relation attention, PAIR-batched kv GEMM with fused
  // scores epilogue (k never materialized; no segment-max, round-5 proven) ----
  for (int pr = 0; pr < 3; ++pr) {
    const int r0 = 2 * pr;
    zero_k<<<391, 256, 0, stream>>>((uint4*)denom2, (2 * NN * NHEAD * 4) / 16);
    // z in {0,1}: relation r0+z. x<2: scores->ex+denom; x>=2: v->kvbuf[z]
    mm_k<3, 0, 4, bf16><<<gKV, 256, 0, stream>>>(
        xb, rel_cat + r0 * 256, 0,
        eidx + (size_t)r0 * 2 * EE, eab + (size_t)r0 * EE * FF,
        prior + r0 * NHEAD,
        Wkvt + (size_t)r0 * 512 * KVP, bkv + r0 * 512, nullptr,
        kvbuf, 256, exden, EE, KVP, 0);
    for (int j = 0; j < 2; ++j) {
      const int r = r0 + j;
      const int* dst = eidx + (size_t)r * 2 * EE + EE;
      zero_k<<<2048, 256, 0, stream>>>((uint4*)agg, (NN * HH * 4) / 16);
      edge2_k<<<EE, 256, 0, stream>>>(
          exden + (size_t)j * EE * NHEAD, kvbuf + (size_t)j * EE * 256, dst, agg);
      // rel[r] = gelu((agg/denom) @ Wm[r] + bm[r]) -> rel_cat slot r
      mm_k<4, 1, 0, bf16><<<gN, 256, 0, stream>>>(
          agg, nullptr, 256, nullptr, nullptr, denom2 + (size_t)j * NN * NHEAD,
          Wmt + (size_t)r * 256 * 256, bm + r * HH, nullptr,
          rel_cat + r * 256, 1536, nullptr, NN, 256, 0);
    }
  }

  // ---- phase 2: inter-relation chain (consumes rel_cat BEFORE meta overwrites) ----
  mm_k<0, 1, 0, bf16><<<gN, 256, 0, stream>>>(
      rel_cat, nullptr, 1536, nullptr, nullptr, nullptr,
      Wir1t, b_ir1, nullptr, hbuf, 256, nullptr, NN, 1536, 0);
  interw_k<<<(NN + 3) / 4, 256, 0, stream>>>(hbuf, W_ir2, b_ir2, interw);
  interagg_k<<<NN, 256, 0, stream>>>(interw, rel_cat, comb);

  // ---- phase 3: meta-path chain (z-batched into tmp, then copy to slots) ----
  mm_k<2, 0, 3, bf16><<<gMP2, 256, 0, stream>>>(
      rel_cat, rel_cat, 1536, nullptr, nullptr, nullptr,
      Wmpt, bmp, nullptr, tmp, 256, nullptr, NN, 256, 0);
  copyslot_k<<<(NN * 32 + 255) / 256, 256, 0, stream>>>(tmp, rel_cat + 2 * 256);
  copyslot_k<<<(NN * 32 + 255) / 256, 256, 0, stream>>>(tmp + (size_t)NN * 256, rel_cat + 4 * 256);
  mm_k<2, 0, 3, bf16><<<gMP1, 256, 0, stream>>>(
      rel_cat, rel_cat, 1536, nullptr, nullptr, nullptr,
      Wmpt, bmp, nullptr, tmp, 256, nullptr, NN, 256, 2);
  copyslot_k<<<(NN * 32 + 255) / 256, 256, 0, stream>>>(tmp, rel_cat + 1 * 256);

  zero_k<<<147, 256, 0, stream>>>((uint4*)logits, (3 * NN * 4) / 16);
  // logits[z] = sum_i tanh(stacked[z] @ Wa1 + ba1)_i * Wa2_i  (z=3 batched)
  mm_k<0, 0, 1, bf16><<<gL, 256, 0, stream>>>(
      rel_cat, nullptr, 1536, nullptr, nullptr, nullptr,
      Wa1t, ba1, Wa2, (bf16*)nullptr, 0, logits, NN, 256, 0);
  metafinal_k<<<(NN + 3) / 4, 256, 0, stream>>>(logits, rel_cat, g_meta, b_meta, comb);

  // ---- phase 4: combine + output LN (d_out) ----
  mm_k<0, 1, 0, float><<<gN, 256, 0, stream>>>(
      comb, nullptr, 512, nullptr, nullptr, nullptr,
      Wct, bc, nullptr, combined, 256, nullptr, NN, 512, 0);
  final_k<<<NN, 256, 0, stream>>>(x, combined, g_out, b_out, out);
}

// Round 8
// 1431.991 us; speedup vs baseline: 1.0373x; 1.0181x over previous
//
#include <hip/hip_runtime.h>
#include <hip/hip_bf16.h>

typedef __hip_bfloat16 bf16;
typedef __attribute__((ext_vector_type(8))) short short8;
typedef __attribute__((ext_vector_type(4))) float f32x4;

#define NN 50000
#define RR 6
#define EE 32768
#define HH 256
#define FF 16
#define NHEAD 8
#define KVP 320   // 272 padded to multiple of 64

struct __align__(8) bf16x4 { bf16 v[4]; };

__device__ __forceinline__ float b2f(bf16 v) { return __bfloat162float(v); }
__device__ __forceinline__ bf16 f2b(float v) { return __float2bfloat16(v); }
__device__ __forceinline__ short f2s(float f) { bf16 b = f2b(f); return __builtin_bit_cast(short, b); }
__device__ __forceinline__ float s2f(short s) { return b2f(__builtin_bit_cast(bf16, s)); }
__device__ __forceinline__ float gelu_f(float x) { return 0.5f * x * (1.0f + erff(x * 0.7071067811865476f)); }

// async global->LDS, 16B per lane (dest = wave-uniform base + lane*16;
// the GLOBAL address may be fully per-lane -> gather-capable)
__device__ __forceinline__ void gl2lds16(const void* g, void* l) {
  __builtin_amdgcn_global_load_lds(
      (const __attribute__((address_space(1))) unsigned int*)g,
      (__attribute__((address_space(3))) unsigned int*)l, 16, 0, 0);
}

// grid-stride zero fill (16B granules)
__global__ void zero_k(uint4* __restrict__ p, int n16)
{
  const uint4 z = make_uint4(0u, 0u, 0u, 0u);
  for (int i = blockIdx.x * blockDim.x + threadIdx.x; i < n16; i += gridDim.x * blockDim.x)
    p[i] = z;
}

// fp32 -> bf16 elementwise (4 per thread)
__global__ void cvt_k(const float* __restrict__ in, bf16* __restrict__ out, int n4)
{
  const int i = blockIdx.x * 256 + threadIdx.x;
  if (i >= n4) return;
  const float4 f = ((const float4*)in)[i];
  bf16x4 o; o.v[0] = f2b(f.x); o.v[1] = f2b(f.y); o.v[2] = f2b(f.z); o.v[3] = f2b(f.w);
  ((bf16x4*)out)[i] = o;
}

// transpose-convert: in fp32 [K][NC] -> out bf16 [NC][Kp], zero-pad K..Kp.
__global__ void tconv_k(const float* __restrict__ in, bf16* __restrict__ out,
                        int K, int NC, int Kp, long izs, long ozs)
{
  __shared__ float t[32][33];
  in  += (size_t)blockIdx.z * izs;
  out += (size_t)blockIdx.z * ozs;
  const int kb = blockIdx.x * 32, nb = blockIdx.y * 32;
  const int tx = threadIdx.x & 31, ty = threadIdx.x >> 5;  // ty 0..7
  for (int i = ty; i < 32; i += 8) {
    const int k = kb + i, n = nb + tx;
    t[i][tx] = (k < K && n < NC) ? in[(size_t)k * NC + n] : 0.f;
  }
  __syncthreads();
  for (int i = ty; i < 32; i += 8) {
    const int n = nb + i, k = kb + tx;
    if (n < NC && k < Kp) out[(size_t)n * Kp + k] = f2b(t[tx][i]);
  }
}

// build concatenated kv bias: bkv[r][0..255]=bk[r], bkv[r][256..511]=bv[r]
__global__ void bkv_k(const float* __restrict__ bk, const float* __restrict__ bv,
                      float* __restrict__ bkv)
{
  const int i = blockIdx.x * 256 + threadIdx.x;
  if (i >= RR * 512) return;
  const int r = i >> 9, c = i & 511;
  bkv[i] = (c < 256) ? bk[r * 256 + c] : bv[r * 256 + (c - 256)];
}

// copy tmp [N][256] bf16 -> rel_cat slot (ld 1536)
__global__ void copyslot_k(const bf16* __restrict__ tmp, bf16* __restrict__ slot)
{
  const int i = blockIdx.x * 256 + threadIdx.x;  // 8-elem chunk id
  if (i >= NN * 32) return;
  const int n = i >> 5, c = (i & 31) * 8;
  *(short8*)(slot + (size_t)n * 1536 + c) = *(const short8*)(tmp + (size_t)n * 256 + c);
}

// ---------------------------------------------------------------------------
// MFMA GEMM (round-5 proven 1-phase, 32KB LDS, ~3 blocks/CU):
// C[M,NC] = act(A[M,K] @ Bt^T + bias), Bt = [NC][K] bf16 k-contig.
// 128x128 tile, BK=64, 4 waves, each wave 64x64 (4x4 of 16x16x32 MFMA).
// LDS chunk (row, cg) holds global chunk cg ^ (row&7) (bank swizzle, staging
// stays lane-contiguous / gl2lds-legal).
// ASRC: 0=A bf16 async; 2=PAIR bf16 sum (reg-staged); 3=KV gather reg-staged
//       (xb[src[r]] bf16 | eab bf16 | zero pad); 4=A fp32 scaled by
//       1/(dnm[row,head]+1e-16) (softmax-normalize fused into staging).
// ZMODE: 0=plain; 1=logits (A = rel_cat+slot3[z]*256, epilogue
//        atomicAdd(logits[z*M+row], sum tanh(c+bias)*wa2));
//        3=metapath batch (z picks pair slots + B/bias, C += z*M*256);
//        4=K-SCORES (z = relation pair member): A = kv gather, B = Wk slab;
//        epilogue gathers q[dst[e]] into the (free) LDS, dots against the
//        fp32 k acc (+bias), 16-lane shuffle-reduce, writes
//        ex=exp(s*scale*prior) + atomicAdds denom. k never materialized.
//        logits param = ex||denom region: ex=[2][E][8] then denom=[2][N][8].
//        5=V-SCATTER (per relation): A = kv gather, B = Wv slab (pre-offset);
//        epilogue does agg[dst[e]] += ex[e,h]*(v+bias) directly (fp32
//        atomics) — replaces the kvbuf round-trip + separate edge2 pass.
//        dnm = ex, logits = agg, bias pre-offset to the v half.
// ---------------------------------------------------------------------------
template<int ASRC, int ACT, int ZMODE, typename TO>
__global__ __launch_bounds__(256) void mm_k(
    const void* __restrict__ Av, const bf16* __restrict__ A2, int lda,
    const int* __restrict__ src, const bf16* __restrict__ eab,
    const float* __restrict__ dnm,
    const bf16* __restrict__ Bt, const float* __restrict__ bias,
    const float* __restrict__ wa2, TO* __restrict__ C, int ldc,
    float* __restrict__ logits, int M, int K, int z0)
{
  __shared__ short lds[2 * 128 * 64];   // lA = lds[0..8191], lB = lds[8192..]
  const int tid = threadIdx.x;
  const int w = tid >> 6, l = tid & 63;
  const int col0 = blockIdx.x << 7;
  const int row0 = blockIdx.y << 7;
  const bf16* Ab = (const bf16*)Av;
  const bf16* A2b = A2;
  const bf16* Btz = Bt;
  const float* biasz = bias;
  TO* Cz = C;
  float* lg = logits;
  const int* srcz = src;
  const int* dstz = nullptr;
  const bf16* eabz = eab;
  const bf16* qz = nullptr;
  float* exbz = nullptr;
  float* dnmaz = nullptr;
  const float* priz = nullptr;
  if constexpr (ZMODE == 1) {
    const int slots3[3] = {2, 4, 1};
    Ab = (const bf16*)Av + slots3[blockIdx.z] * 256;
    lg = logits + (size_t)blockIdx.z * M;
  } else if constexpr (ZMODE == 3) {
    const int r1s[3] = {2, 4, 1}, r2s[3] = {3, 0, 5};
    const int z = blockIdx.z + z0;
    Ab  = (const bf16*)Av + (size_t)r1s[z] * 256;
    A2b = A2 + (size_t)r2s[z] * 256;
    Btz = Bt + (size_t)z * 256 * K;
    biasz = bias + z * 256;
    Cz = C + (size_t)blockIdx.z * (size_t)M * 256;
  } else if constexpr (ZMODE == 4) {
    const int z = blockIdx.z;
    srcz  = src + (size_t)z * 2 * EE;
    dstz  = srcz + EE;
    eabz  = eab + (size_t)z * EE * FF;
    qz    = A2 + z * 256;                 // rel_cat q slot (row stride 1536)
    Btz   = Bt + (size_t)z * 512 * KVP;   // k rows 0..255 of the [512][KVP] slab
    biasz = bias + z * 512;
    exbz  = logits + (size_t)z * EE * NHEAD;
    dnmaz = logits + (size_t)2 * EE * NHEAD + (size_t)z * NN * NHEAD;
    priz  = dnm + z * NHEAD;
  } else if constexpr (ZMODE == 5) {
    dstz = src + EE;                      // per-relation dst row
  }
  const int wm = (w >> 1) << 6, wn = (w & 1) << 6;
  const int lane15 = l & 15, kq = l >> 4;

  f32x4 acc[4][4] = {};

  for (int k0 = 0; k0 < K; k0 += 64) {
    // stage A tile [128][64] (swizzled chunks)
#pragma unroll
    for (int i = 0; i < 4; ++i) {
      const int idx = (w * 4 + i) * 64 + l;        // 0..1023 16B chunks
      const int row = idx >> 3, cg = idx & 7;
      const int scg = cg ^ (row & 7);
      const int r = min(row0 + row, M - 1);
      const int kc = k0 + scg * 8;
      if constexpr (ASRC == 0) {
        gl2lds16(Ab + (size_t)r * lda + kc, &lds[idx * 8]);
      } else if constexpr (ASRC == 2) {
        const short8 u  = *(const short8*)(Ab  + (size_t)r * lda + kc);
        const short8 v2 = *(const short8*)(A2b + (size_t)r * lda + kc);
        short8 s;
#pragma unroll
        for (int j = 0; j < 8; ++j) s[j] = f2s(s2f(u[j]) + s2f(v2[j]));
        *(short8*)&lds[idx * 8] = s;
      } else if constexpr (ASRC == 3) {  // kv gather: xb bf16 | eab bf16 | pad
        short8 s;
        if (kc < HH) {
          s = *(const short8*)((const bf16*)Av + (size_t)srcz[r] * HH + kc);
        } else if (kc < HH + FF) {
          s = *(const short8*)(eabz + (size_t)r * FF + (kc - HH));
        } else {
#pragma unroll
          for (int j = 0; j < 8; ++j) s[j] = 0;
        }
        *(short8*)&lds[idx * 8] = s;
      } else {  // ASRC == 4: fp32 agg scaled by 1/(denom+1e-16), chunk in one head
        const float* p = (const float*)Av + (size_t)r * lda + kc;
        const float4 f0 = *(const float4*)p;
        const float4 f1 = *(const float4*)(p + 4);
        const float iv = 1.0f / (dnm[r * NHEAD + (kc >> 5)] + 1e-16f);
        short8 s;
        s[0] = f2s(f0.x * iv); s[1] = f2s(f0.y * iv); s[2] = f2s(f0.z * iv); s[3] = f2s(f0.w * iv);
        s[4] = f2s(f1.x * iv); s[5] = f2s(f1.y * iv); s[6] = f2s(f1.z * iv); s[7] = f2s(f1.w * iv);
        *(short8*)&lds[idx * 8] = s;
      }
    }
    // stage B tile [128][64] (swizzled, async; block's 128 cols always in range)
#pragma unroll
    for (int i = 0; i < 4; ++i) {
      const int idx = (w * 4 + i) * 64 + l;
      const int row = idx >> 3, cg = idx & 7;
      const int scg = cg ^ (row & 7);
      gl2lds16(Btz + (size_t)(col0 + row) * K + k0 + scg * 8, &lds[8192 + idx * 8]);
    }
    __syncthreads();
#pragma unroll
    for (int kk = 0; kk < 64; kk += 32) {
      short8 af[4], bfr[4];
#pragma unroll
      for (int t = 0; t < 4; ++t) {
        const int ra = wm + t * 16 + lane15;
        const int ca = ((kk >> 3) + kq) ^ (ra & 7);
        af[t] = *(const short8*)&lds[ra * 64 + ca * 8];
        const int rb = wn + t * 16 + lane15;
        const int cb = ((kk >> 3) + kq) ^ (rb & 7);
        bfr[t] = *(const short8*)&lds[8192 + rb * 64 + cb * 8];
      }
#pragma unroll
      for (int ti = 0; ti < 4; ++ti)
#pragma unroll
        for (int tj = 0; tj < 4; ++tj)
          acc[ti][tj] = __builtin_amdgcn_mfma_f32_16x16x32_bf16(af[ti], bfr[tj], acc[ti][tj], 0, 0, 0);
    }
    __syncthreads();
  }

  if constexpr (ZMODE == 4) {
    // ---- scores epilogue: gather q[dst[e]][col0..col0+127] into 32KB LDS ----
#pragma unroll
    for (int i = 0; i < 8; ++i) {
      const int idx = (w * 8 + i) * 64 + l;     // 0..2047 16B chunks
      const int row = idx >> 4, cg = idx & 15;  // 16 chunks per 128-col row
      const int d = dstz[row0 + row];
      gl2lds16(qz + (size_t)d * 1536 + col0 + cg * 8, &lds[idx * 8]);
    }
    __syncthreads();   // drains vmcnt(0) for gl2lds
    const int hb = (col0 + wn) >> 5;            // head of tj=0,1; tj=2,3 -> hb+1
    const float pr0 = priz[hb], pr1 = priz[hb + 1];
#pragma unroll
    for (int ti = 0; ti < 4; ++ti) {
#pragma unroll
      for (int reg = 0; reg < 4; ++reg) {
        const int row = wm + ti * 16 + kq * 4 + reg;   // local row (edge)
        float p0 = 0.f, p1 = 0.f;
#pragma unroll
        for (int tj = 0; tj < 4; ++tj) {
          const int colL = wn + tj * 16 + lane15;      // local col 0..127
          const float kv_ = acc[ti][tj][reg] + biasz[col0 + colL];  // fp32 k
          const float qv = s2f(lds[(row << 7) + colL]);
          if (tj < 2) p0 += qv * kv_; else p1 += qv * kv_;
        }
#pragma unroll
        for (int off = 1; off < 16; off <<= 1) {
          p0 += __shfl_xor(p0, off, 64);
          p1 += __shfl_xor(p1, off, 64);
        }
        if (lane15 == 0) {
          const int e = row0 + row;
          const int d = dstz[e];
          const float e0 = expf(p0 * 0.1767766952966369f * pr0);
          const float e1 = expf(p1 * 0.1767766952966369f * pr1);
          exbz[e * NHEAD + hb]     = e0;
          exbz[e * NHEAD + hb + 1] = e1;
          atomicAdd(&dnmaz[d * NHEAD + hb],     e0);
          atomicAdd(&dnmaz[d * NHEAD + hb + 1], e1);
        }
      }
    }
  } else if constexpr (ZMODE == 5) {
    // ---- v-scatter epilogue: agg[dst[e]] += ex[e,h] * (v + bias) ----
#pragma unroll
    for (int ti = 0; ti < 4; ++ti) {
#pragma unroll
      for (int reg = 0; reg < 4; ++reg) {
        const int e = row0 + wm + ti * 16 + kq * 4 + reg;
        const int d = dstz[e];
        float* ap = lg + (size_t)d * HH;   // lg = agg
#pragma unroll
        for (int tj = 0; tj < 4; ++tj) {
          const int col = col0 + wn + tj * 16 + lane15;        // local v col
          const float wgt = dnm[e * NHEAD + ((col0 + wn + tj * 16) >> 5)];
          atomicAdd(ap + col, wgt * (acc[ti][tj][reg] + biasz[col]));
        }
      }
    }
  } else if constexpr (ZMODE != 1) {
    // C layout: col = lane&15, row = (lane>>4)*4 + reg  [m89-verified]
#pragma unroll
    for (int ti = 0; ti < 4; ++ti) {
#pragma unroll
      for (int reg = 0; reg < 4; ++reg) {
        const int row = row0 + wm + ti * 16 + kq * 4 + reg;
        if (row >= M) continue;
#pragma unroll
        for (int tj = 0; tj < 4; ++tj) {
          const int col = col0 + wn + tj * 16 + lane15;
          float v = acc[ti][tj][reg] + biasz[col];
          if constexpr (ACT == 1) v = gelu_f(v);
          if constexpr (sizeof(TO) == 2) Cz[(size_t)row * ldc + col] = (TO)f2b(v);
          else                           Cz[(size_t)row * ldc + col] = (TO)v;
        }
      }
    }
  } else {
#pragma unroll
    for (int ti = 0; ti < 4; ++ti) {
#pragma unroll
      for (int reg = 0; reg < 4; ++reg) {
        float part = 0.f;
#pragma unroll
        for (int tj = 0; tj < 4; ++tj) {
          const int col = col0 + wn + tj * 16 + lane15;
          part += tanhf(acc[ti][tj][reg] + biasz[col]) * wa2[col];
        }
#pragma unroll
        for (int off = 8; off > 0; off >>= 1) part += __shfl_xor(part, off, 64);
        const int row = row0 + wm + ti * 16 + kq * 4 + reg;
        if (lane15 == 0 && row < M) atomicAdd(&lg[row], part);
      }
    }
  }
}

// ---------------------------------------------------------------------------
// inter-relation softmax weights; one wave per node
// ---------------------------------------------------------------------------
__global__ void interw_k(const bf16* __restrict__ h, const float* __restrict__ W2,
                         const float* __restrict__ b2, float* __restrict__ interw)
{
  const int wv = threadIdx.x >> 6, ln = threadIdx.x & 63;
  const int n = blockIdx.x * 4 + wv;
  if (n >= NN) return;
  float a[6] = {0.f, 0.f, 0.f, 0.f, 0.f, 0.f};
#pragma unroll
  for (int kq = 0; kq < 4; ++kq) {
    const int k = ln + (kq << 6);
    const float hv = b2f(h[(size_t)n * HH + k]);
#pragma unroll
    for (int j = 0; j < 6; ++j) a[j] += hv * W2[k * 6 + j];
  }
#pragma unroll
  for (int j = 0; j < 6; ++j) {
#pragma unroll
    for (int off = 32; off > 0; off >>= 1) a[j] += __shfl_down(a[j], off, 64);
  }
  if (ln == 0) {
    float lg[6], e[6], mx = -1e30f, s = 0.f;
#pragma unroll
    for (int j = 0; j < 6; ++j) { lg[j] = a[j] + b2[j]; mx = fmaxf(mx, lg[j]); }
#pragma unroll
    for (int j = 0; j < 6; ++j) { e[j] = expf(lg[j] - mx); s += e[j]; }
    const float inv = 1.0f / s;
#pragma unroll
    for (int j = 0; j < 6; ++j) interw[(size_t)n * 6 + j] = e[j] * inv;
  }
}

// rel_cat layout: [N][R*256]
__global__ void interagg_k(const float* __restrict__ interw, const bf16* __restrict__ rel_cat,
                           bf16* __restrict__ comb)
{
  const int n = blockIdx.x, t = threadIdx.x;
  float acc = 0.f;
#pragma unroll
  for (int r = 0; r < 6; ++r)
    acc += interw[(size_t)n * 6 + r] * b2f(rel_cat[(size_t)n * 1536 + r * 256 + t]);
  comb[(size_t)n * 512 + t] = f2b(acc);
}

// ---------------------------------------------------------------------------
// meta final: softmax(logits[3]) -> weighted sum of stacked -> LN -> comb[:,256:]
// ---------------------------------------------------------------------------
__global__ void metafinal_k(const float* __restrict__ logits, const bf16* __restrict__ rel_cat,
                            const float* __restrict__ gmeta, const float* __restrict__ bmeta,
                            bf16* __restrict__ comb)
{
  const int wv = threadIdx.x >> 6, ln = threadIdx.x & 63;
  const int n = blockIdx.x * 4 + wv;
  if (n >= NN) return;
  const float l0 = logits[n], l1 = logits[NN + n], l2 = logits[2 * NN + n];
  const float mx = fmaxf(l0, fmaxf(l1, l2));
  const float e0 = expf(l0 - mx), e1 = expf(l1 - mx), e2 = expf(l2 - mx);
  const float inv = 1.0f / (e0 + e1 + e2);
  const float a0 = e0 * inv, a1 = e1 * inv, a2 = e2 * inv;
  const size_t base = (size_t)n * 1536;
  float pre[4], s = 0.f, s2 = 0.f;
#pragma unroll
  for (int q4 = 0; q4 < 4; ++q4) {
    const int j = ln + (q4 << 6);
    const float v = a0 * b2f(rel_cat[base + 2 * 256 + j])
                  + a1 * b2f(rel_cat[base + 4 * 256 + j])
                  + a2 * b2f(rel_cat[base + 1 * 256 + j]);
    pre[q4] = v; s += v; s2 += v * v;
  }
#pragma unroll
  for (int off = 32; off > 0; off >>= 1) { s += __shfl_down(s, off, 64); s2 += __shfl_down(s2, off, 64); }
  s = __shfl(s, 0, 64); s2 = __shfl(s2, 0, 64);
  const float mu = s * (1.0f / 256.0f);
  const float var = s2 * (1.0f / 256.0f) - mu * mu;
  const float rs = rsqrtf(var + 1e-5f);
#pragma unroll
  for (int q4 = 0; q4 < 4; ++q4) {
    const int j = ln + (q4 << 6);
    comb[(size_t)n * 512 + 256 + j] = f2b((pre[q4] - mu) * rs * gmeta[j] + bmeta[j]);
  }
}

// final: out = LN(x + combined)
__global__ void final_k(const float* __restrict__ x, const float* __restrict__ combined,
                        const float* __restrict__ g, const float* __restrict__ b,
                        float* __restrict__ out)
{
  __shared__ float sred[8];
  const int n = blockIdx.x, t = threadIdx.x;
  const float v = x[(size_t)n * HH + t] + combined[(size_t)n * HH + t];
  float s = v, s2 = v * v;
#pragma unroll
  for (int off = 32; off > 0; off >>= 1) { s += __shfl_down(s, off, 64); s2 += __shfl_down(s2, off, 64); }
  const int wv = t >> 6;
  if ((t & 63) == 0) { sred[wv] = s; sred[4 + wv] = s2; }
  __syncthreads();
  const float st = sred[0] + sred[1] + sred[2] + sred[3];
  const float st2 = sred[4] + sred[5] + sred[6] + sred[7];
  const float mu = st * (1.0f / 256.0f);
  const float var = st2 * (1.0f / 256.0f) - mu * mu;
  const float rs = rsqrtf(var + 1e-5f);
  out[(size_t)n * HH + t] = (v - mu) * rs * g[t] + b[t];
}

// ---------------------------------------------------------------------------
extern "C" void kernel_launch(void* const* d_in, const int* in_sizes, int n_in,
                              void* d_out, int out_size, void* d_ws, size_t ws_size,
                              hipStream_t stream)
{
  const float* x      = (const float*)d_in[0];
  const int*   eidx   = (const int*)d_in[1];
  const float* eattr  = (const float*)d_in[2];
  const float* Wq     = (const float*)d_in[3];
  const float* bq     = (const float*)d_in[4];
  const float* Wk     = (const float*)d_in[5];
  const float* bk     = (const float*)d_in[6];
  const float* Wv     = (const float*)d_in[7];
  const float* bv     = (const float*)d_in[8];
  const float* prior  = (const float*)d_in[9];
  const float* Wm     = (const float*)d_in[10];
  const float* bm     = (const float*)d_in[11];
  const float* W_ir1  = (const float*)d_in[12];
  const float* b_ir1  = (const float*)d_in[13];
  const float* W_ir2  = (const float*)d_in[14];
  const float* b_ir2  = (const float*)d_in[15];
  const float* Wmp    = (const float*)d_in[16];
  const float* bmp    = (const float*)d_in[17];
  const float* Wa1    = (const float*)d_in[18];
  const float* ba1    = (const float*)d_in[19];
  const float* Wa2    = (const float*)d_in[20];
  const float* g_meta = (const float*)d_in[21];
  const float* b_meta = (const float*)d_in[22];
  const float* Wc     = (const float*)d_in[23];
  const float* bc     = (const float*)d_in[24];
  const float* g_out  = (const float*)d_in[25];
  const float* b_out  = (const float*)d_in[26];
  float* out = (float*)d_out;

  // ---- workspace layout: PEAK ~229.4 MB (< 235.88 MB proven safe) ----
  char* ws = (char*)d_ws;
  bf16* rel_cat = (bf16*)ws;                         // [N][1536] bf16 = 153,600,000
  char* W0 = ws + 153600000;                         // weights: 5,058,560
  bf16*  Wqt   = (bf16*)(W0 + 0);          // [1536][256]   (6 relations stacked on NC)
  bf16*  Wkvt  = (bf16*)(W0 + 786432);     // [6][512][320] (k rows 0..255, v rows 256..511)
  bf16*  Wmt   = (bf16*)(W0 + 2752512);    // [6][256][256]
  bf16*  Wir1t = (bf16*)(W0 + 3538944);    // [256][1536]
  bf16*  Wct   = (bf16*)(W0 + 4325376);    // [256][512]
  bf16*  Wmpt  = (bf16*)(W0 + 4587520);    // [3][256][256]
  bf16*  Wa1t  = (bf16*)(W0 + 4980736);    // [128][256]
  float* bkv   = (float*)(W0 + 5046272);   // [6][512] fp32 (end 5,058,560)
  char* region = ws + 158658560;
  // phase-1 views (kvbuf eliminated — v scatters straight from the GEMM)
  float* exden  = (float*)(region + 0);              // ex [2][E][8] = 2,097,152
  float* denom2 = exden + 2 * EE * NHEAD;            // denom [2][N][8] = 3,200,000 (end 5,297,152)
  bf16*  xb     = (bf16*)(region + 38851584);        // [N][256] bf16 = 25,600,000 (end 64,451,584)
  bf16*  eab    = (bf16*)(region + 64451584);        // [6][E][16] bf16 = 6,291,456 (end 70,743,040)
  float* agg    = out;                               // d_out as fp32 accumulator (phase 1)
  // phase-2 overlay (exden/denom2 dead)
  bf16*  hbuf     = (bf16*)(region + 0);             // 25,600,000
  float* interw   = (float*)(region + 33554432);     //  1,200,000
  // phase-3 overlay (hbuf/interw/xb dead)
  bf16*  tmp      = (bf16*)(region + 0);             // [2][N][256] = 51,200,000
  float* logits   = (float*)(region + 51200000);     //    600,000 (end 51,800,000)
  // phase-5
  bf16*  comb     = (bf16*)out;                      // [N][512] bf16 in d_out
  float* combined = (float*)(region + 0);            // [N][256] fp32 (tmp dead; logits above)

  // grids: x = col tiles, y = row tiles (A-tile L2 reuse across x)
  const dim3 gN(2, 391);       // M=50000, NC=256
  const dim3 gQ(12, 391);      // M=50000, NC=1536 (batched q)
  const dim3 gK(2, 256, 2);    // k-scores: M=32768, NC=256, z=relation pair
  const dim3 gV(2, 256);       // v-scatter: M=32768, NC=256, per relation
  const dim3 gMP2(2, 391, 2);  // metapath batch z=0,1
  const dim3 gMP1(2, 391, 1);  // metapath batch z=2
  const dim3 gL(1, 391, 3);    // M=50000, NC=128, z=3 meta-paths (logits)

  // ---- phase 0: weight transpose/convert + x->bf16 + eattr->bf16 ----
  tconv_k<<<dim3(8, 8, 6), 256, 0, stream>>>(Wq, Wqt, 256, 256, 256, 256 * 256, 256 * 256);
  tconv_k<<<dim3(10, 8, 6), 256, 0, stream>>>(Wk, Wkvt, 272, 256, 320, 272 * 256, 512 * 320);
  tconv_k<<<dim3(10, 8, 6), 256, 0, stream>>>(Wv, Wkvt + 256 * 320, 272, 256, 320, 272 * 256, 512 * 320);
  tconv_k<<<dim3(8, 8, 6), 256, 0, stream>>>(Wm, Wmt, 256, 256, 256, 256 * 256, 256 * 256);
  tconv_k<<<dim3(48, 8, 1), 256, 0, stream>>>(W_ir1, Wir1t, 1536, 256, 1536, 0, 0);
  tconv_k<<<dim3(16, 8, 1), 256, 0, stream>>>(Wc, Wct, 512, 256, 512, 0, 0);
  tconv_k<<<dim3(8, 8, 3), 256, 0, stream>>>(Wmp, Wmpt, 256, 256, 256, 256 * 256, 256 * 256);
  tconv_k<<<dim3(8, 4, 1), 256, 0, stream>>>(Wa1, Wa1t, 256, 128, 256, 0, 0);
  bkv_k<<<12, 256, 0, stream>>>(bk, bv, bkv);
  cvt_k<<<(NN * 64 + 255) / 256, 256, 0, stream>>>(x, xb, NN * 64);
  cvt_k<<<(RR * EE * FF / 4 + 255) / 256, 256, 0, stream>>>(eattr, eab, RR * EE * FF / 4);

  // ---- phase 1a: ALL q in one GEMM (bf16 A, pure async staging) -> rel_cat.
  // Slot r is consumed by the k-scores GEMM epilogue BEFORE Wm overwrites it. ----
  mm_k<0, 0, 0, bf16><<<gQ, 256, 0, stream>>>(
      xb, nullptr, 256, nullptr, nullptr, nullptr,
      Wqt, bq, nullptr, rel_cat, 1536, nullptr, NN, 256, 0);

  // ---- phase 1b: per-relation attention. Pair-batched k-scores GEMM
  // (k never materialized) then per-relation v-scatter GEMM (v never
  // materialized — agg accumulated in the epilogue) + Wm. ----
  for (int pr = 0; pr < 3; ++pr) {
    const int r0 = 2 * pr;
    zero_k<<<391, 256, 0, stream>>>((uint4*)denom2, (2 * NN * NHEAD * 4) / 16);
    mm_k<3, 0, 4, bf16><<<gK, 256, 0, stream>>>(
        xb, rel_cat + r0 * 256, 0,
        eidx + (size_t)r0 * 2 * EE, eab + (size_t)r0 * EE * FF,
        prior + r0 * NHEAD,
        Wkvt + (size_t)r0 * 512 * KVP, bkv + r0 * 512, nullptr,
        (bf16*)nullptr, 0, exden, EE, KVP, 0);
    for (int j = 0; j < 2; ++j) {
      const int r = r0 + j;
      zero_k<<<2048, 256, 0, stream>>>((uint4*)agg, (NN * HH * 4) / 16);
      // v-scatter GEMM: agg[dst] += ex * ([xb[src]||eab||0] @ Wv + bv)
      mm_k<3, 0, 5, bf16><<<gV, 256, 0, stream>>>(
          xb, nullptr, 0,
          eidx + (size_t)r * 2 * EE, eab + (size_t)r * EE * FF,
          exden + (size_t)j * EE * NHEAD,
          Wkvt + (size_t)r * 512 * KVP + (size_t)256 * KVP, bkv + r * 512 + 256,
          nullptr, (bf16*)nullptr, 0, agg, EE, KVP, 0);
      // rel[r] = gelu((agg/denom) @ Wm[r] + bm[r]) -> rel_cat slot r
      mm_k<4, 1, 0, bf16><<<gN, 256, 0, stream>>>(
          agg, nullptr, 256, nullptr, nullptr, denom2 + (size_t)j * NN * NHEAD,
          Wmt + (size_t)r * 256 * 256, bm + r * HH, nullptr,
          rel_cat + r * 256, 1536, nullptr, NN, 256, 0);
    }
  }

  // ---- phase 2: inter-relation chain (consumes rel_cat BEFORE meta overwrites) ----
  mm_k<0, 1, 0, bf16><<<gN, 256, 0, stream>>>(
      rel_cat, nullptr, 1536, nullptr, nullptr, nullptr,
      Wir1t, b_ir1, nullptr, hbuf, 256, nullptr, NN, 1536, 0);
  interw_k<<<(NN + 3) / 4, 256, 0, stream>>>(hbuf, W_ir2, b_ir2, interw);
  interagg_k<<<NN, 256, 0, stream>>>(interw, rel_cat, comb);

  // ---- phase 3: meta-path chain (z-batched into tmp, then copy to slots) ----
  mm_k<2, 0, 3, bf16><<<gMP2, 256, 0, stream>>>(
      rel_cat, rel_cat, 1536, nullptr, nullptr, nullptr,
      Wmpt, bmp, nullptr, tmp, 256, nullptr, NN, 256, 0);
  copyslot_k<<<(NN * 32 + 255) / 256, 256, 0, stream>>>(tmp, rel_cat + 2 * 256);
  copyslot_k<<<(NN * 32 + 255) / 256, 256, 0, stream>>>(tmp + (size_t)NN * 256, rel_cat + 4 * 256);
  mm_k<2, 0, 3, bf16><<<gMP1, 256, 0, stream>>>(
      rel_cat, rel_cat, 1536, nullptr, nullptr, nullptr,
      Wmpt, bmp, nullptr, tmp, 256, nullptr, NN, 256, 2);
  copyslot_k<<<(NN * 32 + 255) / 256, 256, 0, stream>>>(tmp, rel_cat + 1 * 256);

  zero_k<<<147, 256, 0, stream>>>((uint4*)logits, (3 * NN * 4) / 16);
  // logits[z] = sum_i tanh(stacked[z] @ Wa1 + ba1)_i * Wa2_i  (z=3 batched)
  mm_k<0, 0, 1, bf16><<<gL, 256, 0, stream>>>(
      rel_cat, nullptr, 1536, nullptr, nullptr, nullptr,
      Wa1t, ba1, Wa2, (bf16*)nullptr, 0, logits, NN, 256, 0);
  metafinal_k<<<(NN + 3) / 4, 256, 0, stream>>>(logits, rel_cat, g_meta, b_meta, comb);

  // ---- phase 4: combine + output LN (d_out) ----
  mm_k<0, 1, 0, float><<<gN, 256, 0, stream>>>(
      comb, nullptr, 512, nullptr, nullptr, nullptr,
      Wct, bc, nullptr, combined, 256, nullptr, NN, 512, 0);
  final_k<<<NN, 256, 0, stream>>>(x, combined, g_out, b_out, out);
}